// Round 1
// baseline (682.853 us; speedup 1.0000x reference)
//
#include <hip/hip_runtime.h>

#define BATCH 16
#define NN 1000
#define DD 256
#define KMAX 512

#define META_STRIDE 2560   // ints per batch: inv1[1000], inv2[1000], order[512], U
#define TPAD 1024          // padded column stride of T

#define BM 64
#define BN 64
#define BK 16

// ---------------- Kernel A: per-batch metadata ----------------
// inv1/inv2 (inverse permutations), order[0..U) = ascending union node ids, U.
__global__ __launch_bounds__(256) void meta_kernel(
    const int* __restrict__ idx1, const int* __restrict__ idx2,
    const int* __restrict__ k1, const int* __restrict__ k2,
    int* __restrict__ meta) {
  int b = blockIdx.x;
  int t = threadIdx.x;
  int* inv1 = meta + (size_t)b * META_STRIDE;
  int* inv2 = inv1 + NN;
  int* order = inv2 + NN;
  int* Uptr = order + KMAX;
  const int* i1 = idx1 + (size_t)b * NN;
  const int* i2 = idx2 + (size_t)b * NN;
  for (int j = t; j < NN; j += 256) {
    inv1[i1[j]] = j;
    inv2[i2[j]] = j;
  }
  __syncthreads();
  int kk1 = k1[b], kk2 = k2[b];
  __shared__ int sc[256];
  __shared__ int sU;
  int base = t * 4;
  int un[4];
  int cnt = 0;
  for (int i = 0; i < 4; ++i) {
    int v = base + i;
    int u = 0;
    if (v < NN) u = (inv1[v] < kk1) || (inv2[v] < kk2);
    un[i] = u;
    cnt += u;
  }
  sc[t] = cnt;
  __syncthreads();
  // Hillis-Steele inclusive scan over 256 thread-counts
  for (int off = 1; off < 256; off <<= 1) {
    int v = (t >= off) ? sc[t - off] : 0;
    __syncthreads();
    sc[t] += v;
    __syncthreads();
  }
  int pref = sc[t] - cnt;  // exclusive prefix
  for (int i = 0; i < 4; ++i) {
    if (un[i]) order[pref++] = base + i;
  }
  if (t == 255) {
    sU = sc[255];
    *Uptr = sc[255];
  }
  __syncthreads();
  int U = sU;
  for (int r = U + t; r < KMAX; r += 256) order[r] = 0;  // safe gather index
}

// ---------------- Kernel B: new_H + new_mask ----------------
__global__ __launch_bounds__(256) void feat_kernel(
    const float* __restrict__ H1, const float* __restrict__ H2,
    const int* __restrict__ k1, const int* __restrict__ k2,
    const int* __restrict__ meta,
    float* __restrict__ outH, float* __restrict__ outMask) {
  int r = blockIdx.x;  // 0..KMAX-1
  int b = blockIdx.y;
  int t = threadIdx.x;  // 0..255 == feature
  const int* inv1 = meta + (size_t)b * META_STRIDE;
  const int* inv2 = inv1 + NN;
  const int* order = inv2 + NN;
  int U = order[KMAX];
  float* oH = outH + ((size_t)b * KMAX + r) * DD;
  if (r >= U) {
    oH[t] = 0.f;
    if (t == 0) outMask[(size_t)b * KMAX + r] = 0.f;
    return;
  }
  int v = order[r];
  int j1 = inv1[v];
  int j2 = inv2[v];
  bool in1 = j1 < k1[b];
  bool in2 = j2 < k2[b];
  const float* h1 = H1 + ((size_t)b * NN + j1) * DD;
  const float* h2 = H2 + ((size_t)b * NN + j2) * DD;
  float h;
  if (in1 && in2) h = 0.5f * (h1[t] + h2[t]);
  else if (in1) h = h1[t];
  else h = h2[t];
  oH[t] = h;
  if (t == 0) outMask[(size_t)b * KMAX + r] = 1.f;
}

// ---------------- Kernel C: T = Sg @ adj  (gathered rows of adj times adj) ----------------
// grid: (colTiles=16, rowTiles=8, nb); Tb per-batch [KMAX x TPAD]
__global__ __launch_bounds__(256) void gemm1_kernel(
    const float* __restrict__ adj, const int* __restrict__ meta,
    float* __restrict__ Tbuf, int bbase) {
  int bz = blockIdx.z;
  int b = bz + bbase;
  int rt = blockIdx.y;
  int ct = blockIdx.x;
  const int* order = meta + (size_t)b * META_STRIDE + 2 * NN;
  int U = order[KMAX];
  if (rt * BM >= U) return;  // rows never read downstream
  const float* A = adj + (size_t)b * NN * NN;
  float* Tb = Tbuf + (size_t)bz * KMAX * TPAD;

  __shared__ float As[BK][BM + 1];
  __shared__ float Bs[BK][BN + 1];

  int tid = threadIdx.x;
  int tx = tid & 15;
  int ty = tid >> 4;
  float c[4][4] = {};

  // preload gather indices for this row tile (4 rows per thread-pass pattern)
  int nkt = (NN + BK - 1) / BK;  // 63
  for (int kt = 0; kt < nkt; ++kt) {
    int k0 = kt * BK;
    // load A tile: As[kk][m] = adj[order[rt*64+m]][k0+kk]
    {
      int kk = tid & 15;
      int mrow = tid >> 4;
      int k = k0 + kk;
#pragma unroll
      for (int pass = 0; pass < 4; ++pass) {
        int m = mrow + pass * 16;
        int grow = rt * BM + m;
        float v = 0.f;
        if (grow < U && k < NN) v = A[(size_t)order[grow] * NN + k];
        As[kk][m] = v;
      }
    }
    // load B tile: Bs[kk][n] = adj[k0+kk][ct*64+n]
    {
      int n = tid & 63;
      int kr = tid >> 6;  // 0..3
      int gcol = ct * BN + n;
#pragma unroll
      for (int pass = 0; pass < 4; ++pass) {
        int kk = kr + pass * 4;
        int k = k0 + kk;
        float v = 0.f;
        if (k < NN && gcol < NN) v = A[(size_t)k * NN + gcol];
        Bs[kk][n] = v;
      }
    }
    __syncthreads();
#pragma unroll
    for (int kk = 0; kk < BK; ++kk) {
      float a0 = As[kk][ty * 4 + 0], a1 = As[kk][ty * 4 + 1];
      float a2 = As[kk][ty * 4 + 2], a3 = As[kk][ty * 4 + 3];
      float b0 = Bs[kk][tx * 4 + 0], b1 = Bs[kk][tx * 4 + 1];
      float b2 = Bs[kk][tx * 4 + 2], b3 = Bs[kk][tx * 4 + 3];
      c[0][0] += a0 * b0; c[0][1] += a0 * b1; c[0][2] += a0 * b2; c[0][3] += a0 * b3;
      c[1][0] += a1 * b0; c[1][1] += a1 * b1; c[1][2] += a1 * b2; c[1][3] += a1 * b3;
      c[2][0] += a2 * b0; c[2][1] += a2 * b1; c[2][2] += a2 * b2; c[2][3] += a2 * b3;
      c[3][0] += a3 * b0; c[3][1] += a3 * b1; c[3][2] += a3 * b2; c[3][3] += a3 * b3;
    }
    __syncthreads();
  }
#pragma unroll
  for (int i = 0; i < 4; ++i) {
    int grow = rt * BM + ty * 4 + i;
    if (grow >= U) continue;
#pragma unroll
    for (int j = 0; j < 4; ++j) {
      int gcol = ct * BN + tx * 4 + j;
      if (gcol < NN) Tb[(size_t)grow * TPAD + gcol] = c[i][j];
    }
  }
}

// ---------------- Kernel D: new_adj = T @ Sg^T ----------------
// grid: (8, 8, nb). Writes the FULL 512x512 block (zeros beyond U).
__global__ __launch_bounds__(256) void gemm2_kernel(
    const float* __restrict__ adj, const int* __restrict__ meta,
    const float* __restrict__ Tbuf, float* __restrict__ outAdj, int bbase) {
  int bz = blockIdx.z;
  int b = bz + bbase;
  int rt = blockIdx.y;
  int ct = blockIdx.x;
  const int* order = meta + (size_t)b * META_STRIDE + 2 * NN;
  int U = order[KMAX];
  const float* A = adj + (size_t)b * NN * NN;
  const float* Tb = Tbuf + (size_t)bz * KMAX * TPAD;
  float* O = outAdj + (size_t)b * KMAX * KMAX;

  __shared__ float As[BK][BM + 1];
  __shared__ float Bs[BK][BN + 1];

  int tid = threadIdx.x;
  int tx = tid & 15;
  int ty = tid >> 4;
  float c[4][4] = {};

  bool skip = (rt * BM >= U) || (ct * BN >= U);
  if (!skip) {
    int nkt = (NN + BK - 1) / BK;
    for (int kt = 0; kt < nkt; ++kt) {
      int k0 = kt * BK;
      // As[kk][m] = T[rt*64+m][k0+kk]
      {
        int kk = tid & 15;
        int mrow = tid >> 4;
        int k = k0 + kk;
#pragma unroll
        for (int pass = 0; pass < 4; ++pass) {
          int m = mrow + pass * 16;
          int grow = rt * BM + m;
          float v = 0.f;
          if (grow < U && k < NN) v = Tb[(size_t)grow * TPAD + k];
          As[kk][m] = v;
        }
      }
      // Bs[kk][n] = adj[order[ct*64+n]][k0+kk]
      {
        int kk = tid & 15;
        int nrow = tid >> 4;
        int k = k0 + kk;
#pragma unroll
        for (int pass = 0; pass < 4; ++pass) {
          int n = nrow + pass * 16;
          int gc = ct * BN + n;
          float v = 0.f;
          if (gc < U && k < NN) v = A[(size_t)order[gc] * NN + k];
          Bs[kk][n] = v;
        }
      }
      __syncthreads();
#pragma unroll
      for (int kk = 0; kk < BK; ++kk) {
        float a0 = As[kk][ty * 4 + 0], a1 = As[kk][ty * 4 + 1];
        float a2 = As[kk][ty * 4 + 2], a3 = As[kk][ty * 4 + 3];
        float b0 = Bs[kk][tx * 4 + 0], b1 = Bs[kk][tx * 4 + 1];
        float b2 = Bs[kk][tx * 4 + 2], b3 = Bs[kk][tx * 4 + 3];
        c[0][0] += a0 * b0; c[0][1] += a0 * b1; c[0][2] += a0 * b2; c[0][3] += a0 * b3;
        c[1][0] += a1 * b0; c[1][1] += a1 * b1; c[1][2] += a1 * b2; c[1][3] += a1 * b3;
        c[2][0] += a2 * b0; c[2][1] += a2 * b1; c[2][2] += a2 * b2; c[2][3] += a2 * b3;
        c[3][0] += a3 * b0; c[3][1] += a3 * b1; c[3][2] += a3 * b2; c[3][3] += a3 * b3;
      }
      __syncthreads();
    }
  }
#pragma unroll
  for (int i = 0; i < 4; ++i) {
    int grow = rt * BM + ty * 4 + i;
#pragma unroll
    for (int j = 0; j < 4; ++j) {
      int gcol = ct * BN + tx * 4 + j;
      float v = (grow < U && gcol < U) ? c[i][j] : 0.f;
      O[(size_t)grow * KMAX + gcol] = v;
    }
  }
}

extern "C" void kernel_launch(void* const* d_in, const int* in_sizes, int n_in,
                              void* d_out, int out_size, void* d_ws, size_t ws_size,
                              hipStream_t stream) {
  const float* adj = (const float*)d_in[0];
  const float* H1 = (const float*)d_in[1];
  const float* H2 = (const float*)d_in[2];
  const int* idx1 = (const int*)d_in[3];
  const int* idx2 = (const int*)d_in[4];
  const int* k1 = (const int*)d_in[5];
  const int* k2 = (const int*)d_in[6];

  float* outH = (float*)d_out;                                  // [B,KMAX,DD]
  float* outAdj = outH + (size_t)BATCH * KMAX * DD;             // [B,KMAX,KMAX]
  float* outMask = outAdj + (size_t)BATCH * KMAX * KMAX;        // [B,KMAX]

  int* meta = (int*)d_ws;
  size_t meta_bytes = (size_t)BATCH * META_STRIDE * sizeof(int);  // 160 KB
  size_t meta_al = (meta_bytes + 255) & ~(size_t)255;
  float* Tbuf = (float*)((char*)d_ws + meta_al);
  size_t T_one = (size_t)KMAX * TPAD * sizeof(float);  // 2 MB per batch

  meta_kernel<<<dim3(BATCH), 256, 0, stream>>>(idx1, idx2, k1, k2, meta);
  feat_kernel<<<dim3(KMAX, BATCH), 256, 0, stream>>>(H1, H2, k1, k2, meta, outH, outMask);

  int colTiles = (NN + BN - 1) / BN;  // 16
  int rowTiles = KMAX / BM;           // 8
  int adjTiles = KMAX / BN;           // 8

  if (ws_size >= meta_al + (size_t)BATCH * T_one) {
    // all batches in flight
    gemm1_kernel<<<dim3(colTiles, rowTiles, BATCH), 256, 0, stream>>>(adj, meta, Tbuf, 0);
    gemm2_kernel<<<dim3(adjTiles, rowTiles, BATCH), 256, 0, stream>>>(adj, meta, Tbuf, outAdj, 0);
  } else {
    // per-batch staging, serialized by stream order
    for (int b = 0; b < BATCH; ++b) {
      gemm1_kernel<<<dim3(colTiles, rowTiles, 1), 256, 0, stream>>>(adj, meta, Tbuf, b);
      gemm2_kernel<<<dim3(adjTiles, rowTiles, 1), 256, 0, stream>>>(adj, meta, Tbuf, outAdj, b);
    }
  }
}

// Round 2
// 84.814 us; speedup vs baseline: 8.0512x; 8.0512x over previous
//
#include <hip/hip_runtime.h>

#define BATCH 16
#define NN 1000
#define DD 256
#define KMAX 512

#define META_STRIDE 2560   // ints per batch: inv1[1000], inv2[1000], order[512], U
#define APAD 1024          // padded rows/cols of adjb, and K stride of T

typedef __attribute__((ext_vector_type(8))) short bf16x8;
typedef __attribute__((ext_vector_type(4))) float f32x4;
typedef __attribute__((ext_vector_type(8))) unsigned short ushort8;

// ---------------- Kernel A: per-batch metadata ----------------
__global__ __launch_bounds__(256) void meta_kernel(
    const int* __restrict__ idx1, const int* __restrict__ idx2,
    const int* __restrict__ k1, const int* __restrict__ k2,
    int* __restrict__ meta) {
  int b = blockIdx.x;
  int t = threadIdx.x;
  int* inv1 = meta + (size_t)b * META_STRIDE;
  int* inv2 = inv1 + NN;
  int* order = inv2 + NN;
  int* Uptr = order + KMAX;
  const int* i1 = idx1 + (size_t)b * NN;
  const int* i2 = idx2 + (size_t)b * NN;
  for (int j = t; j < NN; j += 256) {
    inv1[i1[j]] = j;
    inv2[i2[j]] = j;
  }
  __syncthreads();
  int kk1 = k1[b], kk2 = k2[b];
  __shared__ int sc[256];
  __shared__ int sU;
  int base = t * 4;
  int un[4];
  int cnt = 0;
  for (int i = 0; i < 4; ++i) {
    int v = base + i;
    int u = 0;
    if (v < NN) u = (inv1[v] < kk1) || (inv2[v] < kk2);
    un[i] = u;
    cnt += u;
  }
  sc[t] = cnt;
  __syncthreads();
  for (int off = 1; off < 256; off <<= 1) {
    int v = (t >= off) ? sc[t - off] : 0;
    __syncthreads();
    sc[t] += v;
    __syncthreads();
  }
  int pref = sc[t] - cnt;
  for (int i = 0; i < 4; ++i) {
    if (un[i]) order[pref++] = base + i;
  }
  if (t == 255) {
    sU = sc[255];
    *Uptr = sc[255];
  }
  __syncthreads();
  int U = sU;
  for (int r = U + t; r < KMAX; r += 256) order[r] = 0;  // safe gather index
}

// ---------------- Kernel B: new_H + new_mask ----------------
__global__ __launch_bounds__(256) void feat_kernel(
    const float* __restrict__ H1, const float* __restrict__ H2,
    const int* __restrict__ k1, const int* __restrict__ k2,
    const int* __restrict__ meta,
    float* __restrict__ outH, float* __restrict__ outMask) {
  int r = blockIdx.x;
  int b = blockIdx.y;
  int t = threadIdx.x;
  const int* inv1 = meta + (size_t)b * META_STRIDE;
  const int* inv2 = inv1 + NN;
  const int* order = inv2 + NN;
  int U = order[KMAX];
  float* oH = outH + ((size_t)b * KMAX + r) * DD;
  if (r >= U) {
    oH[t] = 0.f;
    if (t == 0) outMask[(size_t)b * KMAX + r] = 0.f;
    return;
  }
  int v = order[r];
  int j1 = inv1[v];
  int j2 = inv2[v];
  bool in1 = j1 < k1[b];
  bool in2 = j2 < k2[b];
  const float* h1 = H1 + ((size_t)b * NN + j1) * DD;
  const float* h2 = H2 + ((size_t)b * NN + j2) * DD;
  float h;
  if (in1 && in2) h = 0.5f * (h1[t] + h2[t]);
  else if (in1) h = h1[t];
  else h = h2[t];
  oH[t] = h;
  if (t == 0) outMask[(size_t)b * KMAX + r] = 1.f;
}

// ---------------- Kernel C: f32 adj -> zero-padded bf16 adjb [1024][1024] ----------------
__global__ __launch_bounds__(128) void conv_kernel(
    const float* __restrict__ adj, ushort* __restrict__ adjb, int bbase) {
  int r = blockIdx.x;       // 0..1023
  int bz = blockIdx.y;
  int b = bz + bbase;
  int t = threadIdx.x;      // 0..127, 8 cols each
  int c0 = t * 8;
  ushort8 o = (ushort8)0;
  if (r < NN && t < 125) {  // 125*8 == 1000 exactly
    const float* src = adj + ((size_t)b * NN + r) * NN + c0;
    float4 f0 = *(const float4*)src;
    float4 f1 = *(const float4*)(src + 4);
    o[0] = (ushort)(__float_as_uint(f0.x) >> 16);
    o[1] = (ushort)(__float_as_uint(f0.y) >> 16);
    o[2] = (ushort)(__float_as_uint(f0.z) >> 16);
    o[3] = (ushort)(__float_as_uint(f0.w) >> 16);
    o[4] = (ushort)(__float_as_uint(f1.x) >> 16);
    o[5] = (ushort)(__float_as_uint(f1.y) >> 16);
    o[6] = (ushort)(__float_as_uint(f1.z) >> 16);
    o[7] = (ushort)(__float_as_uint(f1.w) >> 16);
  }
  *(ushort8*)(adjb + ((size_t)bz * APAD + r) * APAD + c0) = o;
}

// ---------------- Unified MFMA GEMM ----------------
// WHICH==1: T[512][1024](bf16) = gather(adjb, order) @ adjb      (uses adj symmetry)
// WHICH==2: outAdj[512][512](f32) = T @ gather(adjb, order)^T
// 128x128 tile, BK=32, 4 waves; global_load_lds(16B) staging with XOR chunk swizzle.
template<int WHICH>
__global__ __launch_bounds__(256) void mm_kernel(
    const ushort* __restrict__ adjb, ushort* __restrict__ Tb,
    const int* __restrict__ meta, float* __restrict__ outAdj, int bbase) {
  int bz = blockIdx.z;
  int b = bz + bbase;
  int rt = blockIdx.y;
  int ct = blockIdx.x;
  const int* order = meta + (size_t)b * META_STRIDE + 2 * NN;
  int U = order[KMAX];
  int tid = threadIdx.x;
  int lane = tid & 63;
  int w = tid >> 6;
  int wr = w >> 1, wc = w & 1;

  __shared__ __align__(16) ushort As[128 * 32];
  __shared__ __align__(16) ushort Bs[128 * 32];
  __shared__ int sOrd[128];

  const ushort* adjbB = adjb + (size_t)bz * APAD * APAD;
  const ushort* TbB = Tb + (size_t)bz * KMAX * APAD;

  bool active;
  if (WHICH == 1) {
    active = (rt * 128 < U);
    if (!active) return;  // rows never consumed downstream
  } else {
    active = (rt * 128 < U) && (ct * 128 < U);
  }

  int gbase = (WHICH == 1) ? rt * 128 : ct * 128;
  if (tid < 128) sOrd[tid] = order[gbase + tid];
  __syncthreads();

  f32x4 acc[4][4] = {};

  if (active) {
    for (int kt = 0; kt < 32; ++kt) {
      int k0 = kt * 32;
      // ---- stage A tile (128 rows x 32 k) ----
#pragma unroll
      for (int i = 0; i < 2; ++i) {
        int p = i * 256 + tid;
        int r = p >> 2, cp = p & 3;
        int c = cp ^ ((r >> 1) & 3);   // pre-swizzled global chunk
        const ushort* src;
        if (WHICH == 1) src = adjbB + (size_t)sOrd[r] * APAD + k0 + c * 8;
        else            src = TbB + (size_t)(rt * 128 + r) * APAD + k0 + c * 8;
        ushort* dst = As + (size_t)(i * 256 + (tid & 192)) * 8;
        __builtin_amdgcn_global_load_lds((const __attribute__((address_space(1))) void*)src,
                                         (__attribute__((address_space(3))) void*)dst, 16, 0, 0);
      }
      // ---- stage B tile (Bt rows = output cols) ----
#pragma unroll
      for (int i = 0; i < 2; ++i) {
        int p = i * 256 + tid;
        int r = p >> 2, cp = p & 3;
        int c = cp ^ ((r >> 1) & 3);
        const ushort* src;
        if (WHICH == 1) src = adjbB + (size_t)(ct * 128 + r) * APAD + k0 + c * 8;
        else            src = adjbB + (size_t)sOrd[r] * APAD + k0 + c * 8;
        ushort* dst = Bs + (size_t)(i * 256 + (tid & 192)) * 8;
        __builtin_amdgcn_global_load_lds((const __attribute__((address_space(1))) void*)src,
                                         (__attribute__((address_space(3))) void*)dst, 16, 0, 0);
      }
      __syncthreads();   // compiler drains vmcnt before barrier

      bf16x8 a[4], bb[4];
#pragma unroll
      for (int m = 0; m < 4; ++m) {
        int row = wr * 64 + m * 16 + (lane & 15);
        int c = (lane >> 4) ^ ((row >> 1) & 3);   // matching read swizzle
        a[m] = *(const bf16x8*)(As + row * 32 + c * 8);
      }
#pragma unroll
      for (int n = 0; n < 4; ++n) {
        int row = wc * 64 + n * 16 + (lane & 15);
        int c = (lane >> 4) ^ ((row >> 1) & 3);
        bb[n] = *(const bf16x8*)(Bs + row * 32 + c * 8);
      }
#pragma unroll
      for (int m = 0; m < 4; ++m)
#pragma unroll
        for (int n = 0; n < 4; ++n)
          acc[m][n] = __builtin_amdgcn_mfma_f32_16x16x32_bf16(a[m], bb[n], acc[m][n], 0, 0, 0);
      __syncthreads();
    }
  }

  // ---- epilogue ----
  if (WHICH == 1) {
    ushort* TbW = Tb + (size_t)bz * KMAX * APAD;
#pragma unroll
    for (int m = 0; m < 4; ++m)
#pragma unroll
      for (int n = 0; n < 4; ++n)
#pragma unroll
        for (int i = 0; i < 4; ++i) {
          int row = rt * 128 + wr * 64 + m * 16 + ((lane >> 4) << 2) + i;
          int col = ct * 128 + wc * 64 + n * 16 + (lane & 15);
          TbW[(size_t)row * APAD + col] = (ushort)(__float_as_uint(acc[m][n][i]) >> 16);
        }
  } else {
    float* O = outAdj + (size_t)b * KMAX * KMAX;
#pragma unroll
    for (int m = 0; m < 4; ++m)
#pragma unroll
      for (int n = 0; n < 4; ++n)
#pragma unroll
        for (int i = 0; i < 4; ++i) {
          int row = rt * 128 + wr * 64 + m * 16 + ((lane >> 4) << 2) + i;
          int col = ct * 128 + wc * 64 + n * 16 + (lane & 15);
          float v = (row < U && col < U) ? acc[m][n][i] : 0.f;
          O[(size_t)row * KMAX + col] = v;
        }
  }
}

extern "C" void kernel_launch(void* const* d_in, const int* in_sizes, int n_in,
                              void* d_out, int out_size, void* d_ws, size_t ws_size,
                              hipStream_t stream) {
  const float* adj = (const float*)d_in[0];
  const float* H1 = (const float*)d_in[1];
  const float* H2 = (const float*)d_in[2];
  const int* idx1 = (const int*)d_in[3];
  const int* idx2 = (const int*)d_in[4];
  const int* k1 = (const int*)d_in[5];
  const int* k2 = (const int*)d_in[6];

  float* outH = (float*)d_out;                              // [B,KMAX,DD]
  float* outAdj = outH + (size_t)BATCH * KMAX * DD;         // [B,KMAX,KMAX]
  float* outMask = outAdj + (size_t)BATCH * KMAX * KMAX;    // [B,KMAX]

  int* meta = (int*)d_ws;
  size_t meta_bytes = (size_t)BATCH * META_STRIDE * sizeof(int);
  size_t meta_al = (meta_bytes + 255) & ~(size_t)255;

  size_t adjb_one = (size_t)APAD * APAD * sizeof(ushort);  // 2 MB
  size_t T_one = (size_t)KMAX * APAD * sizeof(ushort);     // 1 MB
  size_t per_b = adjb_one + T_one;                         // 3 MB

  int chunk = 1;
  if (ws_size > meta_al + per_b)
    chunk = (int)((ws_size - meta_al) / per_b);
  if (chunk > BATCH) chunk = BATCH;
  if (chunk < 1) chunk = 1;

  ushort* adjb = (ushort*)((char*)d_ws + meta_al);
  ushort* Tb = (ushort*)((char*)adjb + (size_t)chunk * adjb_one);

  meta_kernel<<<dim3(BATCH), 256, 0, stream>>>(idx1, idx2, k1, k2, meta);
  feat_kernel<<<dim3(KMAX, BATCH), 256, 0, stream>>>(H1, H2, k1, k2, meta, outH, outMask);

  for (int bb = 0; bb < BATCH; bb += chunk) {
    int nb = (BATCH - bb < chunk) ? (BATCH - bb) : chunk;
    conv_kernel<<<dim3(APAD, nb), 128, 0, stream>>>(adj, adjb, bb);
    mm_kernel<1><<<dim3(8, 4, nb), 256, 0, stream>>>(adjb, Tb, meta, outAdj, bb);
    mm_kernel<2><<<dim3(4, 4, nb), 256, 0, stream>>>(adjb, Tb, meta, outAdj, bb);
  }
}

// Round 3
// 65.843 us; speedup vs baseline: 10.3709x; 1.2881x over previous
//
#include <hip/hip_runtime.h>

#define BATCH 16
#define NN 1000
#define DD 256
#define KMAX 512

#define META_STRIDE 2560   // ints per batch: inv1[1000], inv2[1000], order[512], U
#define APAD 1024          // padded rows/cols of adjb, and K stride of T

typedef __attribute__((ext_vector_type(8))) short bf16x8;
typedef __attribute__((ext_vector_type(4))) float f32x4;
typedef __attribute__((ext_vector_type(8))) unsigned short ushort8;

// ---------------- Kernel A: per-batch metadata ----------------
__global__ __launch_bounds__(256) void meta_kernel(
    const int* __restrict__ idx1, const int* __restrict__ idx2,
    const int* __restrict__ k1, const int* __restrict__ k2,
    int* __restrict__ meta) {
  int b = blockIdx.x;
  int t = threadIdx.x;
  int* inv1 = meta + (size_t)b * META_STRIDE;
  int* inv2 = inv1 + NN;
  int* order = inv2 + NN;
  int* Uptr = order + KMAX;
  const int* i1 = idx1 + (size_t)b * NN;
  const int* i2 = idx2 + (size_t)b * NN;
  for (int j = t; j < NN; j += 256) {
    inv1[i1[j]] = j;
    inv2[i2[j]] = j;
  }
  __syncthreads();
  int kk1 = k1[b], kk2 = k2[b];
  __shared__ int sc[256];
  __shared__ int sU;
  int base = t * 4;
  int un[4];
  int cnt = 0;
  for (int i = 0; i < 4; ++i) {
    int v = base + i;
    int u = 0;
    if (v < NN) u = (inv1[v] < kk1) || (inv2[v] < kk2);
    un[i] = u;
    cnt += u;
  }
  sc[t] = cnt;
  __syncthreads();
  for (int off = 1; off < 256; off <<= 1) {
    int v = (t >= off) ? sc[t - off] : 0;
    __syncthreads();
    sc[t] += v;
    __syncthreads();
  }
  int pref = sc[t] - cnt;
  for (int i = 0; i < 4; ++i) {
    if (un[i]) order[pref++] = base + i;
  }
  if (t == 255) {
    sU = sc[255];
    *Uptr = sc[255];
  }
  __syncthreads();
  int U = sU;
  for (int r = U + t; r < KMAX; r += 256) order[r] = 0;  // safe gather index
}

// ---------------- Kernel B: new_H + new_mask (float4 vectorized) ----------------
// block = 256 threads = 4 rows x 64 lanes (each lane: one float4)
__global__ __launch_bounds__(256) void feat_kernel(
    const float* __restrict__ H1, const float* __restrict__ H2,
    const int* __restrict__ k1, const int* __restrict__ k2,
    const int* __restrict__ meta,
    float* __restrict__ outH, float* __restrict__ outMask) {
  int tid = threadIdx.x;
  int r = blockIdx.x * 4 + (tid >> 6);  // 0..511
  int b = blockIdx.y;
  int l = tid & 63;                     // float4 index within row
  const int* inv1 = meta + (size_t)b * META_STRIDE;
  const int* inv2 = inv1 + NN;
  const int* order = inv2 + NN;
  int U = order[KMAX];
  float4* oH = (float4*)(outH + ((size_t)b * KMAX + r) * DD) + l;
  if (r >= U) {
    *oH = make_float4(0.f, 0.f, 0.f, 0.f);
    if (l == 0) outMask[(size_t)b * KMAX + r] = 0.f;
    return;
  }
  int v = order[r];
  int j1 = inv1[v];
  int j2 = inv2[v];
  bool in1 = j1 < k1[b];
  bool in2 = j2 < k2[b];
  const float4* h1 = (const float4*)(H1 + ((size_t)b * NN + j1) * DD) + l;
  const float4* h2 = (const float4*)(H2 + ((size_t)b * NN + j2) * DD) + l;
  float4 o;
  if (in1 && in2) {
    float4 a = *h1, c = *h2;
    o = make_float4(0.5f * (a.x + c.x), 0.5f * (a.y + c.y),
                    0.5f * (a.z + c.z), 0.5f * (a.w + c.w));
  } else if (in1) {
    o = *h1;
  } else {
    o = *h2;
  }
  *oH = o;
  if (l == 0) outMask[(size_t)b * KMAX + r] = 1.f;
}

// ---------------- Kernel C: f32 adj -> zero-padded bf16 adjb [1024][1024] ----------------
template<bool PIN>
__global__ __launch_bounds__(128) void conv_kernel(
    const float* __restrict__ adj, ushort* __restrict__ adjb, int bbase) {
  int r, bz, b;
  if (PIN) {
    int g = blockIdx.x;
    int xcd = g & 7;
    int slot = g >> 3;           // 0..2047
    bz = xcd + 8 * (slot >> 10); // batch pinned to XCD b%8
    r = slot & 1023;
    b = bz;
  } else {
    r = blockIdx.x;
    bz = blockIdx.y;
    b = bz + bbase;
  }
  int t = threadIdx.x;      // 0..127, 8 cols each
  int c0 = t * 8;
  ushort8 o = (ushort8)0;
  if (r < NN && t < 125) {  // 125*8 == 1000 exactly
    const float* src = adj + ((size_t)b * NN + r) * NN + c0;
    float4 f0 = *(const float4*)src;
    float4 f1 = *(const float4*)(src + 4);
    o[0] = (ushort)(__float_as_uint(f0.x) >> 16);
    o[1] = (ushort)(__float_as_uint(f0.y) >> 16);
    o[2] = (ushort)(__float_as_uint(f0.z) >> 16);
    o[3] = (ushort)(__float_as_uint(f0.w) >> 16);
    o[4] = (ushort)(__float_as_uint(f1.x) >> 16);
    o[5] = (ushort)(__float_as_uint(f1.y) >> 16);
    o[6] = (ushort)(__float_as_uint(f1.z) >> 16);
    o[7] = (ushort)(__float_as_uint(f1.w) >> 16);
  }
  *(ushort8*)(adjb + ((size_t)bz * APAD + r) * APAD + c0) = o;
}

// ---------------- Unified MFMA GEMM, double-buffered 2-phase ----------------
// WHICH==1: T[512][1024](bf16) = gather(adjb, order) @ adjb   (BM=BN=128)
// WHICH==2: outAdj[512][512](f32) = T @ gather(adjb, order)^T (BM=BN=64)
template<int WHICH, int BM, int BN, bool PIN>
__global__ __launch_bounds__(256) void mm_kernel(
    const ushort* __restrict__ adjb, ushort* __restrict__ Tb,
    const int* __restrict__ meta, float* __restrict__ outAdj, int bbase) {
  constexpr int MR = BM / 32;       // frag-rows per wave
  constexpr int NR = BN / 32;
  constexpr int LA = BM / 64;       // global_load_lds per A buffer
  constexpr int LB = BN / 64;
  constexpr int TBITS = (WHICH == 1) ? 5 : 6;  // log2(tiles per batch)
  constexpr int NKT = 32;

  int bz, rt, ct;
  if (PIN) {
    int g = blockIdx.x;
    int xcd = g & 7;
    int slot = g >> 3;
    bz = xcd + 8 * (slot >> TBITS);
    int t = slot & ((1 << TBITS) - 1);
    rt = t >> 3;
    ct = t & 7;
  } else {
    bz = blockIdx.z;
    rt = blockIdx.y;
    ct = blockIdx.x;
  }
  int b = PIN ? bz : (bz + bbase);

  const int* order = meta + (size_t)b * META_STRIDE + 2 * NN;
  int U = order[KMAX];
  int tid = threadIdx.x;
  int lane = tid & 63;
  int w = tid >> 6;
  int wr = w >> 1, wc = w & 1;

  __shared__ __align__(16) ushort A0[BM * 32];
  __shared__ __align__(16) ushort B0[BN * 32];
  __shared__ __align__(16) ushort A1[BM * 32];
  __shared__ __align__(16) ushort B1[BN * 32];
  __shared__ int sOrd[128];

  const ushort* adjbB = adjb + (size_t)bz * APAD * APAD;
  const ushort* TbB = Tb + (size_t)bz * KMAX * APAD;

  bool active;
  if (WHICH == 1) {
    active = (rt * BM < U);
    if (!active) return;  // rows never consumed downstream
  } else {
    active = (rt * BM < U) && (ct * BN < U);
  }

  int nOrd = (WHICH == 1) ? BM : BN;
  int gbase = (WHICH == 1) ? rt * BM : ct * BN;
  if (tid < nOrd) sOrd[tid] = order[gbase + tid];
  __syncthreads();

  f32x4 acc[MR][NR] = {};

#define STAGE(ABUF, BBUF, KT)                                                  \
  {                                                                            \
    int k0 = (KT) * 32;                                                        \
    _Pragma("unroll")                                                          \
    for (int i = 0; i < LA; ++i) {                                             \
      int p = i * 256 + tid;                                                   \
      int r = p >> 2, cp = p & 3;                                              \
      int c = cp ^ ((r >> 1) & 3);                                             \
      const ushort* src = (WHICH == 1)                                         \
          ? adjbB + (size_t)sOrd[r] * APAD + k0 + c * 8                        \
          : TbB + (size_t)(rt * BM + r) * APAD + k0 + c * 8;                   \
      ushort* dst = (ABUF) + (size_t)(i * 256 + (tid & 192)) * 8;              \
      __builtin_amdgcn_global_load_lds(                                        \
          (const __attribute__((address_space(1))) void*)src,                  \
          (__attribute__((address_space(3))) void*)dst, 16, 0, 0);             \
    }                                                                          \
    _Pragma("unroll")                                                          \
    for (int i = 0; i < LB; ++i) {                                             \
      int p = i * 256 + tid;                                                   \
      int r = p >> 2, cp = p & 3;                                              \
      int c = cp ^ ((r >> 1) & 3);                                             \
      const ushort* src = (WHICH == 1)                                         \
          ? adjbB + (size_t)(ct * BN + r) * APAD + k0 + c * 8                  \
          : adjbB + (size_t)sOrd[r] * APAD + k0 + c * 8;                       \
      ushort* dst = (BBUF) + (size_t)(i * 256 + (tid & 192)) * 8;              \
      __builtin_amdgcn_global_load_lds(                                        \
          (const __attribute__((address_space(1))) void*)src,                  \
          (__attribute__((address_space(3))) void*)dst, 16, 0, 0);             \
    }                                                                          \
  }

#define COMPUTE(ABUF, BBUF)                                                    \
  {                                                                            \
    bf16x8 a[MR], bv[NR];                                                      \
    _Pragma("unroll")                                                          \
    for (int m = 0; m < MR; ++m) {                                             \
      int row = wr * (MR * 16) + m * 16 + (lane & 15);                         \
      int c = (lane >> 4) ^ ((row >> 1) & 3);                                  \
      a[m] = *(const bf16x8*)((ABUF) + row * 32 + c * 8);                      \
    }                                                                          \
    _Pragma("unroll")                                                          \
    for (int n = 0; n < NR; ++n) {                                             \
      int row = wc * (NR * 16) + n * 16 + (lane & 15);                         \
      int c = (lane >> 4) ^ ((row >> 1) & 3);                                  \
      bv[n] = *(const bf16x8*)((BBUF) + row * 32 + c * 8);                     \
    }                                                                          \
    _Pragma("unroll")                                                          \
    for (int m = 0; m < MR; ++m)                                               \
      _Pragma("unroll")                                                        \
      for (int n = 0; n < NR; ++n)                                             \
        acc[m][n] = __builtin_amdgcn_mfma_f32_16x16x32_bf16(a[m], bv[n],       \
                                                            acc[m][n], 0, 0, 0);\
  }

  if (active) {
    STAGE(A0, B0, 0);
    __syncthreads();
    for (int kt = 0; kt < NKT; kt += 2) {
      STAGE(A1, B1, kt + 1);     // prefetch while computing A0/B0
      COMPUTE(A0, B0);
      __syncthreads();           // drains vmcnt (A1/B1 ready), protects A0/B0
      if (kt + 2 < NKT) STAGE(A0, B0, kt + 2);
      COMPUTE(A1, B1);
      __syncthreads();
    }
  }
#undef STAGE
#undef COMPUTE

  // ---- epilogue ----
  if (WHICH == 1) {
    ushort* TbW = Tb + (size_t)bz * KMAX * APAD;
#pragma unroll
    for (int m = 0; m < MR; ++m)
#pragma unroll
      for (int n = 0; n < NR; ++n)
#pragma unroll
        for (int i = 0; i < 4; ++i) {
          int row = rt * BM + wr * (MR * 16) + m * 16 + ((lane >> 4) << 2) + i;
          int col = ct * BN + wc * (NR * 16) + n * 16 + (lane & 15);
          TbW[(size_t)row * APAD + col] = (ushort)(__float_as_uint(acc[m][n][i]) >> 16);
        }
  } else {
    float* O = outAdj + (size_t)b * KMAX * KMAX;
#pragma unroll
    for (int m = 0; m < MR; ++m)
#pragma unroll
      for (int n = 0; n < NR; ++n)
#pragma unroll
        for (int i = 0; i < 4; ++i) {
          int row = rt * BM + wr * (MR * 16) + m * 16 + ((lane >> 4) << 2) + i;
          int col = ct * BN + wc * (NR * 16) + n * 16 + (lane & 15);
          float v = (row < U && col < U) ? acc[m][n][i] : 0.f;
          O[(size_t)row * KMAX + col] = v;
        }
  }
}

extern "C" void kernel_launch(void* const* d_in, const int* in_sizes, int n_in,
                              void* d_out, int out_size, void* d_ws, size_t ws_size,
                              hipStream_t stream) {
  const float* adj = (const float*)d_in[0];
  const float* H1 = (const float*)d_in[1];
  const float* H2 = (const float*)d_in[2];
  const int* idx1 = (const int*)d_in[3];
  const int* idx2 = (const int*)d_in[4];
  const int* k1 = (const int*)d_in[5];
  const int* k2 = (const int*)d_in[6];

  float* outH = (float*)d_out;                              // [B,KMAX,DD]
  float* outAdj = outH + (size_t)BATCH * KMAX * DD;         // [B,KMAX,KMAX]
  float* outMask = outAdj + (size_t)BATCH * KMAX * KMAX;    // [B,KMAX]

  int* meta = (int*)d_ws;
  size_t meta_bytes = (size_t)BATCH * META_STRIDE * sizeof(int);
  size_t meta_al = (meta_bytes + 255) & ~(size_t)255;

  size_t adjb_one = (size_t)APAD * APAD * sizeof(ushort);  // 2 MB
  size_t T_one = (size_t)KMAX * APAD * sizeof(ushort);     // 1 MB
  size_t per_b = adjb_one + T_one;                         // 3 MB

  int chunk = 1;
  if (ws_size > meta_al + per_b)
    chunk = (int)((ws_size - meta_al) / per_b);
  if (chunk > BATCH) chunk = BATCH;
  if (chunk < 1) chunk = 1;

  ushort* adjb = (ushort*)((char*)d_ws + meta_al);
  ushort* Tb = (ushort*)((char*)adjb + (size_t)chunk * adjb_one);

  meta_kernel<<<dim3(BATCH), 256, 0, stream>>>(idx1, idx2, k1, k2, meta);
  feat_kernel<<<dim3(KMAX / 4, BATCH), 256, 0, stream>>>(H1, H2, k1, k2, meta, outH, outMask);

  if (chunk == BATCH) {
    // XCD-pinned 1D grids: batch b -> XCD b%8; adjb+T stay in that XCD's L2
    conv_kernel<true><<<dim3(8 * 2048), 128, 0, stream>>>(adj, adjb, 0);
    mm_kernel<1, 128, 128, true><<<dim3(8 * 64), 256, 0, stream>>>(adjb, Tb, meta, outAdj, 0);
    mm_kernel<2, 64, 64, true><<<dim3(8 * 128), 256, 0, stream>>>(adjb, Tb, meta, outAdj, 0);
  } else {
    for (int bb = 0; bb < BATCH; bb += chunk) {
      int nb = (BATCH - bb < chunk) ? (BATCH - bb) : chunk;
      conv_kernel<false><<<dim3(APAD, nb), 128, 0, stream>>>(adj, adjb, bb);
      mm_kernel<1, 128, 128, false><<<dim3(8, 4, nb), 256, 0, stream>>>(adjb, Tb, meta, outAdj, bb);
      mm_kernel<2, 64, 64, false><<<dim3(8, 8, nb), 256, 0, stream>>>(adjb, Tb, meta, outAdj, bb);
    }
  }
}

// Round 4
// 62.657 us; speedup vs baseline: 10.8983x; 1.0509x over previous
//
#include <hip/hip_runtime.h>

#define BATCH 16
#define NN 1000
#define DD 256
#define KMAX 512

#define META_STRIDE 2560   // ints per batch: inv1[1000], inv2[1000], order[512], U
#define APAD 1024          // padded rows/cols of adjb, and K stride of T

typedef __attribute__((ext_vector_type(8))) short bf16x8;
typedef __attribute__((ext_vector_type(4))) float f32x4;
typedef __attribute__((ext_vector_type(8))) unsigned short ushort8;

// ---------------- Kernel A: per-batch metadata ----------------
__global__ __launch_bounds__(256) void meta_kernel(
    const int* __restrict__ idx1, const int* __restrict__ idx2,
    const int* __restrict__ k1, const int* __restrict__ k2,
    int* __restrict__ meta) {
  int b = blockIdx.x;
  int t = threadIdx.x;
  int* inv1 = meta + (size_t)b * META_STRIDE;
  int* inv2 = inv1 + NN;
  int* order = inv2 + NN;
  int* Uptr = order + KMAX;
  const int* i1 = idx1 + (size_t)b * NN;
  const int* i2 = idx2 + (size_t)b * NN;
  for (int j = t; j < NN; j += 256) {
    inv1[i1[j]] = j;
    inv2[i2[j]] = j;
  }
  __syncthreads();
  int kk1 = k1[b], kk2 = k2[b];
  __shared__ int sc[256];
  __shared__ int sU;
  int base = t * 4;
  int un[4];
  int cnt = 0;
  for (int i = 0; i < 4; ++i) {
    int v = base + i;
    int u = 0;
    if (v < NN) u = (inv1[v] < kk1) || (inv2[v] < kk2);
    un[i] = u;
    cnt += u;
  }
  sc[t] = cnt;
  __syncthreads();
  for (int off = 1; off < 256; off <<= 1) {
    int v = (t >= off) ? sc[t - off] : 0;
    __syncthreads();
    sc[t] += v;
    __syncthreads();
  }
  int pref = sc[t] - cnt;
  for (int i = 0; i < 4; ++i) {
    if (un[i]) order[pref++] = base + i;
  }
  if (t == 255) {
    sU = sc[255];
    *Uptr = sc[255];
  }
  __syncthreads();
  int U = sU;
  for (int r = U + t; r < KMAX; r += 256) order[r] = 0;  // safe gather index
}

// ---------------- Merged prep: conv (f32->bf16 pad) + feat (new_H/new_mask) ----------------
// conv part: blocks [0, 8192): 2 rows of adjb each (256 thr = 2 x 128)
// feat part: blocks [8192, 10240): 4 rows of outH each (256 thr = 4 x 64 float4)
__global__ __launch_bounds__(256) void prep_kernel(
    const float* __restrict__ adj, ushort* __restrict__ adjb,
    const float* __restrict__ H1, const float* __restrict__ H2,
    const int* __restrict__ k1, const int* __restrict__ k2,
    const int* __restrict__ meta,
    float* __restrict__ outH, float* __restrict__ outMask) {
  int g = blockIdx.x;
  int tid = threadIdx.x;
  if (g < 8192) {
    // -------- conv role, XCD-pinned: batch = (g&7) + 8*(slot>>9) --------
    int xcd = g & 7;
    int slot = g >> 3;                 // 0..1023
    int bz = xcd + 8 * (slot >> 9);    // batch
    int rp = slot & 511;               // row pair
    int r = rp * 2 + (tid >> 7);       // 0..1023
    int t = tid & 127;
    int c0 = t * 8;
    ushort8 o = (ushort8)0;
    if (r < NN && t < 125) {           // 125*8 == 1000
      const float* src = adj + ((size_t)bz * NN + r) * NN + c0;
      float4 f0 = *(const float4*)src;
      float4 f1 = *(const float4*)(src + 4);
      o[0] = (ushort)(__float_as_uint(f0.x) >> 16);
      o[1] = (ushort)(__float_as_uint(f0.y) >> 16);
      o[2] = (ushort)(__float_as_uint(f0.z) >> 16);
      o[3] = (ushort)(__float_as_uint(f0.w) >> 16);
      o[4] = (ushort)(__float_as_uint(f1.x) >> 16);
      o[5] = (ushort)(__float_as_uint(f1.y) >> 16);
      o[6] = (ushort)(__float_as_uint(f1.z) >> 16);
      o[7] = (ushort)(__float_as_uint(f1.w) >> 16);
    }
    *(ushort8*)(adjb + ((size_t)bz * APAD + r) * APAD + c0) = o;
  } else {
    // -------- feat role --------
    int f = g - 8192;
    int xcd = f & 7;
    int slot = f >> 3;                 // 0..255
    int b = xcd + 8 * (slot >> 7);
    int rblk = slot & 127;
    int r = rblk * 4 + (tid >> 6);     // 0..511
    int l = tid & 63;
    const int* inv1 = meta + (size_t)b * META_STRIDE;
    const int* inv2 = inv1 + NN;
    const int* order = inv2 + NN;
    int U = order[KMAX];
    float4* oH = (float4*)(outH + ((size_t)b * KMAX + r) * DD) + l;
    if (r >= U) {
      *oH = make_float4(0.f, 0.f, 0.f, 0.f);
      if (l == 0) outMask[(size_t)b * KMAX + r] = 0.f;
      return;
    }
    int v = order[r];
    int j1 = inv1[v];
    int j2 = inv2[v];
    bool in1 = j1 < k1[b];
    bool in2 = j2 < k2[b];
    const float4* h1 = (const float4*)(H1 + ((size_t)b * NN + j1) * DD) + l;
    const float4* h2 = (const float4*)(H2 + ((size_t)b * NN + j2) * DD) + l;
    float4 o;
    if (in1 && in2) {
      float4 a = *h1, c = *h2;
      o = make_float4(0.5f * (a.x + c.x), 0.5f * (a.y + c.y),
                      0.5f * (a.z + c.z), 0.5f * (a.w + c.w));
    } else if (in1) {
      o = *h1;
    } else {
      o = *h2;
    }
    *oH = o;
    if (l == 0) outMask[(size_t)b * KMAX + r] = 1.f;
  }
}

// ---------------- Unified MFMA GEMM, double-buffered 2-phase ----------------
// WHICH==1: T[512][1024](bf16) = gather(adjb, order) @ adjb   (BM=64, BN=128)
// WHICH==2: outAdj[512][512](f32) = T @ gather(adjb, order)^T (BM=BN=64)
template<int WHICH, int BM, int BN, bool PIN>
__global__ __launch_bounds__(256) void mm_kernel(
    const ushort* __restrict__ adjb, ushort* __restrict__ Tb,
    const int* __restrict__ meta, float* __restrict__ outAdj, int bbase) {
  constexpr int MR = BM / 32;       // frag-rows per wave (wave grid 2x2)
  constexpr int NR = BN / 32;
  constexpr int LA = BM / 64;       // global_load_lds batches per A buffer
  constexpr int LB = BN / 64;
  constexpr int CT_TILES = (WHICH == 1 ? APAD : KMAX) / BN;
  constexpr int RT_TILES = KMAX / BM;
  constexpr int TILES = RT_TILES * CT_TILES;   // 64 for both configs
  constexpr int NKT = 32;

  int bz, rt, ct;
  if (PIN) {
    int g = blockIdx.x;
    int xcd = g & 7;
    int slot = g >> 3;                  // 0 .. 2*TILES-1
    bz = xcd + 8 * (slot / TILES);
    int t = slot % TILES;
    rt = t / CT_TILES;
    ct = t % CT_TILES;
  } else {
    bz = blockIdx.z;
    rt = blockIdx.y;
    ct = blockIdx.x;
  }
  int b = PIN ? bz : (bz + bbase);

  const int* order = meta + (size_t)b * META_STRIDE + 2 * NN;
  int U = order[KMAX];
  int tid = threadIdx.x;
  int lane = tid & 63;
  int w = tid >> 6;
  int wr = w >> 1, wc = w & 1;

  __shared__ __align__(16) ushort A0[BM * 32];
  __shared__ __align__(16) ushort B0[BN * 32];
  __shared__ __align__(16) ushort A1[BM * 32];
  __shared__ __align__(16) ushort B1[BN * 32];
  __shared__ int sOrd[128];

  const ushort* adjbB = adjb + (size_t)bz * APAD * APAD;
  const ushort* TbB = Tb + (size_t)bz * KMAX * APAD;

  bool active;
  if (WHICH == 1) {
    active = (rt * BM < U);
    if (!active) return;  // rows never consumed downstream
  } else {
    active = (rt * BM < U) && (ct * BN < U);
  }

  int nOrd = (WHICH == 1) ? BM : BN;
  int gbase = (WHICH == 1) ? rt * BM : ct * BN;
  if (tid < nOrd) sOrd[tid] = order[gbase + tid];
  __syncthreads();

  f32x4 acc[MR][NR] = {};

#define STAGE(ABUF, BBUF, KT)                                                  \
  {                                                                            \
    int k0 = (KT) * 32;                                                        \
    _Pragma("unroll")                                                          \
    for (int i = 0; i < LA; ++i) {                                             \
      int p = i * 256 + tid;                                                   \
      int r = p >> 2, cp = p & 3;                                              \
      int c = cp ^ ((r >> 1) & 3);                                             \
      const ushort* src = (WHICH == 1)                                         \
          ? adjbB + (size_t)sOrd[r] * APAD + k0 + c * 8                        \
          : TbB + (size_t)(rt * BM + r) * APAD + k0 + c * 8;                   \
      ushort* dst = (ABUF) + (size_t)(i * 256 + (tid & 192)) * 8;              \
      __builtin_amdgcn_global_load_lds(                                        \
          (const __attribute__((address_space(1))) void*)src,                  \
          (__attribute__((address_space(3))) void*)dst, 16, 0, 0);             \
    }                                                                          \
    _Pragma("unroll")                                                          \
    for (int i = 0; i < LB; ++i) {                                             \
      int p = i * 256 + tid;                                                   \
      int r = p >> 2, cp = p & 3;                                              \
      int c = cp ^ ((r >> 1) & 3);                                             \
      const ushort* src = (WHICH == 1)                                         \
          ? adjbB + (size_t)(ct * BN + r) * APAD + k0 + c * 8                  \
          : adjbB + (size_t)sOrd[r] * APAD + k0 + c * 8;                       \
      ushort* dst = (BBUF) + (size_t)(i * 256 + (tid & 192)) * 8;              \
      __builtin_amdgcn_global_load_lds(                                        \
          (const __attribute__((address_space(1))) void*)src,                  \
          (__attribute__((address_space(3))) void*)dst, 16, 0, 0);             \
    }                                                                          \
  }

#define COMPUTE(ABUF, BBUF)                                                    \
  {                                                                            \
    bf16x8 a[MR], bv[NR];                                                      \
    _Pragma("unroll")                                                          \
    for (int m = 0; m < MR; ++m) {                                             \
      int row = wr * (MR * 16) + m * 16 + (lane & 15);                         \
      int c = (lane >> 4) ^ ((row >> 1) & 3);                                  \
      a[m] = *(const bf16x8*)((ABUF) + row * 32 + c * 8);                      \
    }                                                                          \
    _Pragma("unroll")                                                          \
    for (int n = 0; n < NR; ++n) {                                             \
      int row = wc * (NR * 16) + n * 16 + (lane & 15);                         \
      int c = (lane >> 4) ^ ((row >> 1) & 3);                                  \
      bv[n] = *(const bf16x8*)((BBUF) + row * 32 + c * 8);                     \
    }                                                                          \
    _Pragma("unroll")                                                          \
    for (int m = 0; m < MR; ++m)                                               \
      _Pragma("unroll")                                                        \
      for (int n = 0; n < NR; ++n)                                             \
        acc[m][n] = __builtin_amdgcn_mfma_f32_16x16x32_bf16(a[m], bv[n],       \
                                                            acc[m][n], 0, 0, 0);\
  }

  if (active) {
    STAGE(A0, B0, 0);
    __syncthreads();
    for (int kt = 0; kt < NKT; kt += 2) {
      STAGE(A1, B1, kt + 1);     // prefetch while computing A0/B0
      COMPUTE(A0, B0);
      __syncthreads();           // drains vmcnt (A1/B1 ready), protects A0/B0
      if (kt + 2 < NKT) STAGE(A0, B0, kt + 2);
      COMPUTE(A1, B1);
      __syncthreads();
    }
  }
#undef STAGE
#undef COMPUTE

  // ---- epilogue ----
  if (WHICH == 1) {
    ushort* TbW = Tb + (size_t)bz * KMAX * APAD;
#pragma unroll
    for (int m = 0; m < MR; ++m)
#pragma unroll
      for (int n = 0; n < NR; ++n)
#pragma unroll
        for (int i = 0; i < 4; ++i) {
          int row = rt * BM + wr * (MR * 16) + m * 16 + ((lane >> 4) << 2) + i;
          int col = ct * BN + wc * (NR * 16) + n * 16 + (lane & 15);
          TbW[(size_t)row * APAD + col] = (ushort)(__float_as_uint(acc[m][n][i]) >> 16);
        }
  } else {
    float* O = outAdj + (size_t)b * KMAX * KMAX;
#pragma unroll
    for (int m = 0; m < MR; ++m)
#pragma unroll
      for (int n = 0; n < NR; ++n)
#pragma unroll
        for (int i = 0; i < 4; ++i) {
          int row = rt * BM + wr * (MR * 16) + m * 16 + ((lane >> 4) << 2) + i;
          int col = ct * BN + wc * (NR * 16) + n * 16 + (lane & 15);
          float v = (row < U && col < U) ? acc[m][n][i] : 0.f;
          O[(size_t)row * KMAX + col] = v;
        }
  }
}

extern "C" void kernel_launch(void* const* d_in, const int* in_sizes, int n_in,
                              void* d_out, int out_size, void* d_ws, size_t ws_size,
                              hipStream_t stream) {
  const float* adj = (const float*)d_in[0];
  const float* H1 = (const float*)d_in[1];
  const float* H2 = (const float*)d_in[2];
  const int* idx1 = (const int*)d_in[3];
  const int* idx2 = (const int*)d_in[4];
  const int* k1 = (const int*)d_in[5];
  const int* k2 = (const int*)d_in[6];

  float* outH = (float*)d_out;                              // [B,KMAX,DD]
  float* outAdj = outH + (size_t)BATCH * KMAX * DD;         // [B,KMAX,KMAX]
  float* outMask = outAdj + (size_t)BATCH * KMAX * KMAX;    // [B,KMAX]

  int* meta = (int*)d_ws;
  size_t meta_bytes = (size_t)BATCH * META_STRIDE * sizeof(int);
  size_t meta_al = (meta_bytes + 255) & ~(size_t)255;

  size_t adjb_one = (size_t)APAD * APAD * sizeof(ushort);  // 2 MB
  size_t T_one = (size_t)KMAX * APAD * sizeof(ushort);     // 1 MB
  size_t per_b = adjb_one + T_one;                         // 3 MB

  int chunk = 1;
  if (ws_size > meta_al + per_b)
    chunk = (int)((ws_size - meta_al) / per_b);
  if (chunk > BATCH) chunk = BATCH;
  if (chunk < 1) chunk = 1;

  ushort* adjb = (ushort*)((char*)d_ws + meta_al);
  ushort* Tb = (ushort*)((char*)adjb + (size_t)chunk * adjb_one);

  meta_kernel<<<dim3(BATCH), 256, 0, stream>>>(idx1, idx2, k1, k2, meta);

  if (chunk == BATCH) {
    // merged conv+feat (one launch), XCD-pinned
    prep_kernel<<<dim3(8192 + 2048), 256, 0, stream>>>(adj, adjb, H1, H2, k1, k2,
                                                       meta, outH, outMask);
    // 64x128 tiles: ~2 active blocks/CU for typical U
    mm_kernel<1, 64, 128, true><<<dim3(8 * 128), 256, 0, stream>>>(adjb, Tb, meta, outAdj, 0);
    mm_kernel<2, 64, 64, true><<<dim3(8 * 128), 256, 0, stream>>>(adjb, Tb, meta, outAdj, 0);
  } else {
    // fallback (small ws): per-batch staging, separate conv path via prep-like loop
    for (int bb = 0; bb < BATCH; bb += chunk) {
      int nb = (BATCH - bb < chunk) ? (BATCH - bb) : chunk;
      // reuse mm fallback grids; conv via prep is PIN-only, so do a simple loop:
      // stage adjb for these batches using the conv part of prep semantics
      // (grid = rows x nb, 256 threads = 2 rows)
      // Simple dedicated conversion:
      for (int q = 0; q < nb; ++q) {
        // one batch at a time: 512 blocks x 2 rows
        // (we fold batch index via bbase pointer offset)
        const float* adj_q = adj + (size_t)(bb + q) * NN * NN;
        ushort* adjb_q = adjb + (size_t)q * APAD * APAD;
        auto conv_lambda = [] __device__ (const float* a, ushort* ab, int blk, int tid) {};
        (void)adj_q; (void)adjb_q; (void)conv_lambda;
      }
      // NOTE: fallback path retained from earlier rounds is impractical here;
      // ws_size has been observed at ~240 MB, chunk==BATCH always holds.
      mm_kernel<1, 64, 128, false><<<dim3(8, 8, nb), 256, 0, stream>>>(adjb, Tb, meta, outAdj, bb);
      mm_kernel<2, 64, 64, false><<<dim3(8, 8, nb), 256, 0, stream>>>(adjb, Tb, meta, outAdj, bb);
    }
  }
}

// Round 5
// 57.786 us; speedup vs baseline: 11.8169x; 1.0843x over previous
//
#include <hip/hip_runtime.h>

#define BATCH 16
#define NN 1000
#define DD 256
#define KMAX 512

#define META_STRIDE 2560   // ints per batch: inv1[1000], inv2[1000], order[512], U
#define APAD 1024          // padded rows/cols of adjb, and K stride of T

typedef __attribute__((ext_vector_type(8))) short bf16x8;
typedef __attribute__((ext_vector_type(4))) float f32x4;
typedef __attribute__((ext_vector_type(8))) unsigned short ushort8;

// ---------------- Kernel A: per-batch metadata ----------------
__global__ __launch_bounds__(256) void meta_kernel(
    const int* __restrict__ idx1, const int* __restrict__ idx2,
    const int* __restrict__ k1, const int* __restrict__ k2,
    int* __restrict__ meta) {
  int b = blockIdx.x;
  int t = threadIdx.x;
  int* inv1 = meta + (size_t)b * META_STRIDE;
  int* inv2 = inv1 + NN;
  int* order = inv2 + NN;
  int* Uptr = order + KMAX;
  const int* i1 = idx1 + (size_t)b * NN;
  const int* i2 = idx2 + (size_t)b * NN;
  for (int j = t; j < NN; j += 256) {
    inv1[i1[j]] = j;
    inv2[i2[j]] = j;
  }
  __syncthreads();
  int kk1 = k1[b], kk2 = k2[b];
  __shared__ int sc[256];
  __shared__ int sU;
  int base = t * 4;
  int un[4];
  int cnt = 0;
  for (int i = 0; i < 4; ++i) {
    int v = base + i;
    int u = 0;
    if (v < NN) u = (inv1[v] < kk1) || (inv2[v] < kk2);
    un[i] = u;
    cnt += u;
  }
  sc[t] = cnt;
  __syncthreads();
  for (int off = 1; off < 256; off <<= 1) {
    int v = (t >= off) ? sc[t - off] : 0;
    __syncthreads();
    sc[t] += v;
    __syncthreads();
  }
  int pref = sc[t] - cnt;
  for (int i = 0; i < 4; ++i) {
    if (un[i]) order[pref++] = base + i;
  }
  if (t == 255) {
    sU = sc[255];
    *Uptr = sc[255];
  }
  __syncthreads();
  int U = sU;
  for (int r = U + t; r < KMAX; r += 256) order[r] = 0;  // safe gather index
}

// ---------------- feat: one output row (64 lanes, float4 each) ----------------
__device__ __forceinline__ void feat_row(
    const float* __restrict__ H1, const float* __restrict__ H2,
    const int* __restrict__ k1, const int* __restrict__ k2,
    const int* __restrict__ meta, float* __restrict__ outH,
    float* __restrict__ outMask, int b, int r, int l) {
  const int* inv1 = meta + (size_t)b * META_STRIDE;
  const int* inv2 = inv1 + NN;
  const int* order = inv2 + NN;
  int U = order[KMAX];
  float4* oH = (float4*)(outH + ((size_t)b * KMAX + r) * DD) + l;
  if (r >= U) {
    *oH = make_float4(0.f, 0.f, 0.f, 0.f);
    if (l == 0) outMask[(size_t)b * KMAX + r] = 0.f;
    return;
  }
  int v = order[r];
  int j1 = inv1[v];
  int j2 = inv2[v];
  bool in1 = j1 < k1[b];
  bool in2 = j2 < k2[b];
  const float4* h1 = (const float4*)(H1 + ((size_t)b * NN + j1) * DD) + l;
  const float4* h2 = (const float4*)(H2 + ((size_t)b * NN + j2) * DD) + l;
  float4 o;
  if (in1 && in2) {
    float4 a = *h1, c = *h2;
    o = make_float4(0.5f * (a.x + c.x), 0.5f * (a.y + c.y),
                    0.5f * (a.z + c.z), 0.5f * (a.w + c.w));
  } else if (in1) {
    o = *h1;
  } else {
    o = *h2;
  }
  *oH = o;
  if (l == 0) outMask[(size_t)b * KMAX + r] = 1.f;
}

// ---------------- fallback feat kernel ----------------
__global__ __launch_bounds__(256) void feat_kernel(
    const float* __restrict__ H1, const float* __restrict__ H2,
    const int* __restrict__ k1, const int* __restrict__ k2,
    const int* __restrict__ meta,
    float* __restrict__ outH, float* __restrict__ outMask, int bbase) {
  int tid = threadIdx.x;
  int r = blockIdx.x * 4 + (tid >> 6);
  int b = blockIdx.y + bbase;
  feat_row(H1, H2, k1, k2, meta, outH, outMask, b, r, tid & 63);
}

// ---------------- conv: f32 adj -> zero-padded bf16 adjb [1024][1024] ----------------
template<bool PIN>
__global__ __launch_bounds__(256) void conv_kernel(
    const float* __restrict__ adj, ushort* __restrict__ adjb, int bbase) {
  int tid = threadIdx.x;
  int r, bz, b;
  if (PIN) {
    int g = blockIdx.x;                // [0, 8192)
    int xcd = g & 7;
    int slot = g >> 3;                 // 0..1023
    bz = xcd + 8 * (slot >> 9);        // batch pinned to XCD b%8
    int rp = slot & 511;
    r = rp * 2 + (tid >> 7);
    b = bz;
  } else {
    r = blockIdx.x * 2 + (tid >> 7);
    bz = blockIdx.y;
    b = bz + bbase;
  }
  int t = tid & 127;
  int c0 = t * 8;
  ushort8 o = (ushort8)0;
  if (r < NN && t < 125) {             // 125*8 == 1000
    const float* src = adj + ((size_t)b * NN + r) * NN + c0;
    float4 f0 = *(const float4*)src;
    float4 f1 = *(const float4*)(src + 4);
    o[0] = (ushort)(__float_as_uint(f0.x) >> 16);
    o[1] = (ushort)(__float_as_uint(f0.y) >> 16);
    o[2] = (ushort)(__float_as_uint(f0.z) >> 16);
    o[3] = (ushort)(__float_as_uint(f0.w) >> 16);
    o[4] = (ushort)(__float_as_uint(f1.x) >> 16);
    o[5] = (ushort)(__float_as_uint(f1.y) >> 16);
    o[6] = (ushort)(__float_as_uint(f1.z) >> 16);
    o[7] = (ushort)(__float_as_uint(f1.w) >> 16);
  }
  *(ushort8*)(adjb + ((size_t)bz * APAD + r) * APAD + c0) = o;
}

// ---------------- Unified MFMA GEMM, BK=64 (2 subtiles), counted-vmcnt ping-pong ----------------
// WHICH==1: T[512][1024](bf16) = gather(adjb, order) @ adjb   (BM=64, BN=128)
// WHICH==2: outAdj[512][512](f32) = T @ gather(adjb, order)^T (BM=BN=64)
template<int WHICH, int BM, int BN, bool PIN, bool FEAT>
__global__ __launch_bounds__(256) void mm_kernel(
    const ushort* __restrict__ adjb, ushort* __restrict__ Tb,
    const int* __restrict__ meta, float* __restrict__ outAdj,
    const float* __restrict__ H1, const float* __restrict__ H2,
    const int* __restrict__ k1, const int* __restrict__ k2,
    float* __restrict__ outH, float* __restrict__ outMask, int bbase) {
  constexpr int MR = BM / 32;
  constexpr int NR = BN / 32;
  constexpr int LA = BM / 64;              // load-instrs per 32-k subtile, A
  constexpr int LB = BN / 64;
  constexpr int LL = 2 * (LA + LB);        // loads per 64-k STAGE
  constexpr int CT_TILES = (WHICH == 1 ? APAD : KMAX) / BN;
  constexpr int RT_TILES = KMAX / BM;
  constexpr int TILES = RT_TILES * CT_TILES;   // 64
  constexpr int NKT2 = APAD / 64;              // 16 outer k-tiles
  constexpr int MMBLK = 8 * 2 * TILES;         // PIN grid mm portion = 1024

  int tid = threadIdx.x;

  // ---- feat tail blocks (PIN main path only) ----
  if (FEAT && PIN && (int)blockIdx.x >= MMBLK) {
    int g2 = blockIdx.x - MMBLK;        // [0, 1024)
    int xcd = g2 & 7;
    int slot = g2 >> 3;                 // 0..127
    int b = xcd + 8 * (slot >> 6);
    int rb = slot & 63;                 // 8 rows each
    int l = tid & 63;
#pragma unroll
    for (int pass = 0; pass < 2; ++pass) {
      int r = rb * 8 + pass * 4 + (tid >> 6);
      feat_row(H1, H2, k1, k2, meta, outH, outMask, b, r, l);
    }
    return;
  }

  int bz, rt, ct;
  if (PIN) {
    int g = blockIdx.x;
    int xcd = g & 7;
    int slot = g >> 3;                  // 0 .. 2*TILES-1
    bz = xcd + 8 * (slot / TILES);
    int tt = slot % TILES;
    rt = tt / CT_TILES;
    ct = tt % CT_TILES;
  } else {
    bz = blockIdx.z;
    rt = blockIdx.y;
    ct = blockIdx.x;
  }
  int b = PIN ? bz : (bz + bbase);

  const int* order = meta + (size_t)b * META_STRIDE + 2 * NN;
  int U = order[KMAX];
  int lane = tid & 63;
  int w = tid >> 6;
  int wr = w >> 1, wc = w & 1;

  __shared__ __align__(16) ushort A0[2 * BM * 32];
  __shared__ __align__(16) ushort B0[2 * BN * 32];
  __shared__ __align__(16) ushort A1[2 * BM * 32];
  __shared__ __align__(16) ushort B1[2 * BN * 32];
  __shared__ int sOrd[128];

  const ushort* adjbB = adjb + (size_t)bz * APAD * APAD;
  const ushort* TbB = Tb + (size_t)bz * KMAX * APAD;

  bool active;
  if (WHICH == 1) {
    active = (rt * BM < U);
    if (!active) return;  // rows never consumed downstream
  } else {
    active = (rt * BM < U) && (ct * BN < U);
  }

  int nOrd = (WHICH == 1) ? BM : BN;
  int gbase = (WHICH == 1) ? rt * BM : ct * BN;
  if (tid < nOrd) sOrd[tid] = order[gbase + tid];
  __syncthreads();

  f32x4 acc[MR][NR] = {};

#define WAITV(N) asm volatile("s_waitcnt vmcnt(%0)" :: "i"(N) : "memory")
#define BAR() do { __builtin_amdgcn_s_barrier(); asm volatile("" ::: "memory"); } while (0)

#define STAGE(ABUF, BBUF, KT)                                                  \
  {                                                                            \
    _Pragma("unroll")                                                          \
    for (int s = 0; s < 2; ++s) {                                              \
      int k0 = (KT) * 64 + s * 32;                                             \
      _Pragma("unroll")                                                        \
      for (int i = 0; i < LA; ++i) {                                           \
        int p = i * 256 + tid;                                                 \
        int r = p >> 2, cp = p & 3;                                            \
        int c = cp ^ ((r >> 1) & 3);                                           \
        const ushort* src = (WHICH == 1)                                       \
            ? adjbB + (size_t)sOrd[r] * APAD + k0 + c * 8                      \
            : TbB + (size_t)(rt * BM + r) * APAD + k0 + c * 8;                 \
        ushort* dst = (ABUF) + s * (BM * 32) + (size_t)(i * 256 + (tid & 192)) * 8; \
        __builtin_amdgcn_global_load_lds(                                      \
            (const __attribute__((address_space(1))) void*)src,                \
            (__attribute__((address_space(3))) void*)dst, 16, 0, 0);           \
      }                                                                        \
      _Pragma("unroll")                                                        \
      for (int i = 0; i < LB; ++i) {                                           \
        int p = i * 256 + tid;                                                 \
        int r = p >> 2, cp = p & 3;                                            \
        int c = cp ^ ((r >> 1) & 3);                                           \
        const ushort* src = (WHICH == 1)                                       \
            ? adjbB + (size_t)(ct * BN + r) * APAD + k0 + c * 8                \
            : adjbB + (size_t)sOrd[r] * APAD + k0 + c * 8;                     \
        ushort* dst = (BBUF) + s * (BN * 32) + (size_t)(i * 256 + (tid & 192)) * 8; \
        __builtin_amdgcn_global_load_lds(                                      \
            (const __attribute__((address_space(1))) void*)src,                \
            (__attribute__((address_space(3))) void*)dst, 16, 0, 0);           \
      }                                                                        \
    }                                                                          \
  }

#define COMPUTE64(ABUF, BBUF)                                                  \
  {                                                                            \
    _Pragma("unroll")                                                          \
    for (int s = 0; s < 2; ++s) {                                              \
      bf16x8 a[MR], bv[NR];                                                    \
      _Pragma("unroll")                                                        \
      for (int m = 0; m < MR; ++m) {                                           \
        int row = wr * (MR * 16) + m * 16 + (lane & 15);                       \
        int c = (lane >> 4) ^ ((row >> 1) & 3);                                \
        a[m] = *(const bf16x8*)((ABUF) + s * (BM * 32) + row * 32 + c * 8);    \
      }                                                                        \
      _Pragma("unroll")                                                        \
      for (int n = 0; n < NR; ++n) {                                           \
        int row = wc * (NR * 16) + n * 16 + (lane & 15);                       \
        int c = (lane >> 4) ^ ((row >> 1) & 3);                                \
        bv[n] = *(const bf16x8*)((BBUF) + s * (BN * 32) + row * 32 + c * 8);   \
      }                                                                        \
      _Pragma("unroll")                                                        \
      for (int m = 0; m < MR; ++m)                                             \
        _Pragma("unroll")                                                      \
        for (int n = 0; n < NR; ++n)                                           \
          acc[m][n] = __builtin_amdgcn_mfma_f32_16x16x32_bf16(a[m], bv[n],     \
                                                              acc[m][n], 0, 0, 0); \
    }                                                                          \
  }

  if (active) {
    STAGE(A0, B0, 0);
    STAGE(A1, B1, 1);
#pragma unroll 1
    for (int t = 0; t < NKT2 - 2; t += 2) {
      WAITV(LL);            // own A0/B0 loads done (A1/B1 still in flight)
      BAR();                // all waves' A0/B0 landed
      COMPUTE64(A0, B0);
      BAR();                // all waves done reading A0/B0
      STAGE(A0, B0, t + 2);
      WAITV(LL);
      BAR();
      COMPUTE64(A1, B1);
      BAR();
      STAGE(A1, B1, t + 3);
    }
    WAITV(LL);
    BAR();
    COMPUTE64(A0, B0);      // tile NKT2-2
    WAITV(0);
    BAR();
    COMPUTE64(A1, B1);      // tile NKT2-1
  }
#undef STAGE
#undef COMPUTE64
#undef WAITV
#undef BAR

  // ---- epilogue ----
  if (WHICH == 1) {
    ushort* TbW = Tb + (size_t)bz * KMAX * APAD;
#pragma unroll
    for (int m = 0; m < MR; ++m)
#pragma unroll
      for (int n = 0; n < NR; ++n)
#pragma unroll
        for (int i = 0; i < 4; ++i) {
          int row = rt * BM + wr * (MR * 16) + m * 16 + ((lane >> 4) << 2) + i;
          int col = ct * BN + wc * (NR * 16) + n * 16 + (lane & 15);
          TbW[(size_t)row * APAD + col] = (ushort)(__float_as_uint(acc[m][n][i]) >> 16);
        }
  } else {
    float* O = outAdj + (size_t)b * KMAX * KMAX;
#pragma unroll
    for (int m = 0; m < MR; ++m)
#pragma unroll
      for (int n = 0; n < NR; ++n)
#pragma unroll
        for (int i = 0; i < 4; ++i) {
          int row = rt * BM + wr * (MR * 16) + m * 16 + ((lane >> 4) << 2) + i;
          int col = ct * BN + wc * (NR * 16) + n * 16 + (lane & 15);
          float v = (row < U && col < U) ? acc[m][n][i] : 0.f;
          O[(size_t)row * KMAX + col] = v;
        }
  }
}

extern "C" void kernel_launch(void* const* d_in, const int* in_sizes, int n_in,
                              void* d_out, int out_size, void* d_ws, size_t ws_size,
                              hipStream_t stream) {
  const float* adj = (const float*)d_in[0];
  const float* H1 = (const float*)d_in[1];
  const float* H2 = (const float*)d_in[2];
  const int* idx1 = (const int*)d_in[3];
  const int* idx2 = (const int*)d_in[4];
  const int* k1 = (const int*)d_in[5];
  const int* k2 = (const int*)d_in[6];

  float* outH = (float*)d_out;                              // [B,KMAX,DD]
  float* outAdj = outH + (size_t)BATCH * KMAX * DD;         // [B,KMAX,KMAX]
  float* outMask = outAdj + (size_t)BATCH * KMAX * KMAX;    // [B,KMAX]

  int* meta = (int*)d_ws;
  size_t meta_bytes = (size_t)BATCH * META_STRIDE * sizeof(int);
  size_t meta_al = (meta_bytes + 255) & ~(size_t)255;

  size_t adjb_one = (size_t)APAD * APAD * sizeof(ushort);  // 2 MB
  size_t T_one = (size_t)KMAX * APAD * sizeof(ushort);     // 1 MB
  size_t per_b = adjb_one + T_one;                         // 3 MB

  int chunk = 1;
  if (ws_size > meta_al + per_b)
    chunk = (int)((ws_size - meta_al) / per_b);
  if (chunk > BATCH) chunk = BATCH;
  if (chunk < 1) chunk = 1;

  ushort* adjb = (ushort*)((char*)d_ws + meta_al);
  ushort* Tb = (ushort*)((char*)adjb + (size_t)chunk * adjb_one);

  meta_kernel<<<dim3(BATCH), 256, 0, stream>>>(idx1, idx2, k1, k2, meta);

  if (chunk == BATCH) {
    conv_kernel<true><<<dim3(8192), 256, 0, stream>>>(adj, adjb, 0);
    // mm1 grid: [0,1024) mm tiles, [1024,2048) feat tail
    mm_kernel<1, 64, 128, true, true><<<dim3(2048), 256, 0, stream>>>(
        adjb, Tb, meta, outAdj, H1, H2, k1, k2, outH, outMask, 0);
    mm_kernel<2, 64, 64, true, false><<<dim3(1024), 256, 0, stream>>>(
        adjb, Tb, meta, outAdj, H1, H2, k1, k2, outH, outMask, 0);
  } else {
    feat_kernel<<<dim3(KMAX / 4, BATCH), 256, 0, stream>>>(H1, H2, k1, k2, meta,
                                                           outH, outMask, 0);
    for (int bb = 0; bb < BATCH; bb += chunk) {
      int nb = (BATCH - bb < chunk) ? (BATCH - bb) : chunk;
      conv_kernel<false><<<dim3(512, nb), 256, 0, stream>>>(adj, adjb, bb);
      mm_kernel<1, 64, 128, false, false><<<dim3(8, 8, nb), 256, 0, stream>>>(
          adjb, Tb, meta, outAdj, H1, H2, k1, k2, outH, outMask, bb);
      mm_kernel<2, 64, 64, false, false><<<dim3(8, 8, nb), 256, 0, stream>>>(
          adjb, Tb, meta, outAdj, H1, H2, k1, k2, outH, outMask, bb);
    }
  }
}